// Round 19
// baseline (164.309 us; speedup 1.0000x reference)
//
#include <hip/hip_runtime.h>

// Window attention, fully fused fp16-MFMA, transposed-output layouts.
// r19 = r18 (reduced accumulator/live footprint) + launch_bounds(256,5)
// (102-reg budget -> 5 waves/SIMD, 5 blocks/CU at 31744B LDS) and bf dbuf
// dropped (-16 VGPR; TLP at 5-wave occupancy covers L2-hot weight latency).
// r18 under (256,4) let the allocator burn the whole 128-reg budget: VGPR
// stayed 64, occupancy stayed 39% -- the footprint cut was never cashed in.
#define B_WIN 4096
#define NTOK 49
#define DIMC 128
#define HEADS 4
#define HD 32
#define NWIN 64
#define MTOT (B_WIN * 49) /* 200704 */
#define SCALE_Q 0.17677669529663687f /* 32^-0.5 */

typedef _Float16 half8 __attribute__((ext_vector_type(8)));
typedef float f32x4 __attribute__((ext_vector_type(4)));
typedef unsigned short ushortv8 __attribute__((ext_vector_type(8)));

__device__ __forceinline__ unsigned short f2h(float f) {
    _Float16 h = (_Float16)f; // RNE
    return __builtin_bit_cast(unsigned short, h);
}
__device__ __forceinline__ unsigned packh2(float a, float b) {
    return (unsigned)f2h(a) | ((unsigned)f2h(b) << 16);
}

struct alignas(8) US4 { unsigned short x, y, z, w; };

#define XSP 136 /* xs pitch (u16) */
#define PW 7840 /* per-wave LDS: Qs[49][40] + Ks[49][40]; Ps[49][72] + Os[49][40] overlay */

// ---------------- prep1: qkv_w f32 -> fp16, B-frag-ordered ----------------
__global__ __launch_bounds__(256) void prep_w2(
    const float* __restrict__ w, unsigned short* __restrict__ w2)
{
    int id = blockIdx.x * 256 + threadIdx.x; // < 4*6*4*64 = 6144
    if (id >= 6144) return;
    int lane = id & 63, ks = (id >> 6) & 3, jt = (id >> 8) % 6, h = id / 1536;
    int c = lane & 15, g = lane >> 4;
    int sec = jt >> 1, dhalf = jt & 1;
    int tb = sec * 128 + h * 32 + dhalf * 16;
    const float* src = w + (size_t)(tb + c) * 128 + 32 * ks + 8 * g;
    ushortv8 p;
#pragma unroll
    for (int j = 0; j < 8; ++j) p[j] = f2h(src[j]);
    *(ushortv8*)(w2 + (size_t)id * 8) = p;
}

// ---------------- prep1b: proj_w f32 -> fp16, B-frag-ordered ----------------
__global__ __launch_bounds__(256) void prep_pw2(
    const float* __restrict__ w, unsigned short* __restrict__ pw2)
{
    int id = blockIdx.x * 256 + threadIdx.x; // < 8*4*64 = 2048
    if (id >= 2048) return;
    int lane = id & 63, ks = (id >> 6) & 3, j8 = id >> 8;
    int c = lane & 15, g = lane >> 4;
    const float* src = w + (size_t)(j8 * 16 + c) * 128 + 32 * ks + 8 * g;
    ushortv8 p;
#pragma unroll
    for (int j = 0; j < 8; ++j) p[j] = f2h(src[j]);
    *(ushortv8*)(pw2 + (size_t)id * 8) = p;
}

// ---------------- prep2: bias+mask f32, lane-ordered for S^T layout ----------------
__global__ __launch_bounds__(256) void prep_cmb2(
    const float* __restrict__ rpb, const int* __restrict__ rpi,
    const float* __restrict__ mask, float* __restrict__ cmb2)
{
    int id = blockIdx.x * 256 + threadIdx.x; // < 64*4*64*64 = 1048576
    int lane = id & 63, idx = (id >> 6) & 63, wh = id >> 12;
    int h = wh & 3, w = wh >> 2;
    int mt = idx >> 4, nt = (idx >> 2) & 3, r = idx & 3;
    int c = lane & 15, g = lane >> 4;
    int m = 16 * mt + c, n = 16 * nt + 4 * g + r; // S^T roles
    float v = 0.f;
    if (m < 49 && n < 49) {
        int e = m * 49 + n;
        v = rpb[rpi[e] * 4 + h] + mask[w * 2401 + e];
    }
    cmb2[id] = v;
}

// ---------------- fully fused kernel ----------------
__global__ __launch_bounds__(256, 5) void attn_fused(
    const float* __restrict__ x, const unsigned short* __restrict__ w2,
    const unsigned short* __restrict__ pw2, const float* __restrict__ qkv_b,
    const float* __restrict__ cmb2, const float* __restrict__ proj_b,
    float* __restrict__ out)
{
    __shared__ __align__(16) char smem[4 * PW];
    const int t = threadIdx.x, wv = t >> 6, lane = t & 63;
    const int c = lane & 15, g = lane >> 4;
    const int gl = g & 1, gh = g >> 1;
    const int b = blockIdx.x, h = wv;

    unsigned short* xs = (unsigned short*)smem;               // [49][136] overlay (dies at qkv)
    unsigned short* Qs = (unsigned short*)(smem + wv * PW);   // [49][40]
    unsigned short* Ks = Qs + 49 * 40;                        // [49][40]
    unsigned short* Ps = Qs;                                  // [49][72] overlay
    unsigned short* Os = Qs;                                  // [49][40] overlay (after PV reads)

    // ---- stage window x: coalesced f32 loads -> fp16 xs ----
    {
        const float* xw = x + (size_t)b * (49 * 128);
#pragma unroll
        for (int it = 0; it < 7; ++it) {
            int idx = it * 256 + t; // 1568 chunks of 4 f32
            if (idx < 1568) {
                int row = idx >> 5, c4 = (idx & 31) * 4;
                float4 v = *(const float4*)(xw + row * 128 + c4);
                US4 p; p.x = f2h(v.x); p.y = f2h(v.y); p.z = f2h(v.z); p.w = f2h(v.w);
                *(US4*)(xs + row * XSP + c4) = p;
            }
        }
    }
    __syncthreads(); // xs staged before frag reads

    // ---- hoist all A-frags from xs (row clamp 48; garbage masked downstream) ----
    half8 af[4][4];
#pragma unroll
    for (int mt = 0; mt < 4; ++mt) {
        const int row = min(16 * mt + c, 48);
#pragma unroll
        for (int ks = 0; ks < 4; ++ks)
            af[mt][ks] = *(const half8*)(xs + row * XSP + 32 * ks + 8 * g);
    }
    __syncthreads(); // all waves done reading xs before Qs/Ks overlay writes

    // ---- qkv gemm: Q/K via swapped mfma (tokens-in-col) -> b64 epi; V -> regs ----
    unsigned vlo[4][2], vhi[4][2]; // V in C-layout packs: [mt][dhalf]
    const unsigned short* wbase = w2 + (size_t)h * 12288;
#pragma unroll
    for (int jt = 0; jt < 6; ++jt) {
        const int sec = jt >> 1, dhalf = jt & 1;
        const int tb = sec * 128 + h * 32 + dhalf * 16;
        half8 bf[4];
#pragma unroll
        for (int ks = 0; ks < 4; ++ks)
            bf[ks] = *(const half8*)(wbase + ((jt * 4 + ks) * 64 + lane) * 8);
        f32x4 acc[4];
#pragma unroll
        for (int mt = 0; mt < 4; ++mt) acc[mt] = (f32x4){0.f, 0.f, 0.f, 0.f};
        if (sec < 2) {
            // swapped: C[i=4g+r -> out-dim][j=c -> token]
#pragma unroll
            for (int ks = 0; ks < 4; ++ks)
#pragma unroll
                for (int mt = 0; mt < 4; ++mt)
                    acc[mt] = __builtin_amdgcn_mfma_f32_16x16x32_f16(bf[ks], af[mt][ks], acc[mt], 0, 0, 0);
            const float4 bv4 = *(const float4*)(qkv_b + tb + 4 * g);
            const float scl = (sec == 0) ? SCALE_Q : 1.0f;
            unsigned short* dstS = (sec == 0) ? Qs : Ks;
#pragma unroll
            for (int mt = 0; mt < 4; ++mt) {
                const int m = 16 * mt + c;
                if (m < 49) {
                    uint2 pk;
                    pk.x = packh2((acc[mt][0] + bv4.x) * scl, (acc[mt][1] + bv4.y) * scl);
                    pk.y = packh2((acc[mt][2] + bv4.z) * scl, (acc[mt][3] + bv4.w) * scl);
                    *(uint2*)(dstS + m * 40 + dhalf * 16 + 4 * g) = pk;
                }
            }
        } else {
            // original orientation for V (feeds the proven shfl path)
#pragma unroll
            for (int ks = 0; ks < 4; ++ks)
#pragma unroll
                for (int mt = 0; mt < 4; ++mt)
                    acc[mt] = __builtin_amdgcn_mfma_f32_16x16x32_f16(af[mt][ks], bf[ks], acc[mt], 0, 0, 0);
            const float bv = qkv_b[tb + c];
#pragma unroll
            for (int mt = 0; mt < 4; ++mt) {
                vlo[mt][dhalf] = packh2(acc[mt][0] + bv, acc[mt][1] + bv);
                vhi[mt][dhalf] = packh2(acc[mt][2] + bv, acc[mt][3] + bv);
            }
        }
    }

    // ---- hoist Q/K frags (clamped rows) BEFORE Ps overlay clobbers Qs/Ks ----
    half8 qf[4], kf[4];
#pragma unroll
    for (int mt = 0; mt < 4; ++mt)
        qf[mt] = *(const half8*)(Qs + min(16 * mt + c, 48) * 40 + 8 * g);
#pragma unroll
    for (int nt = 0; nt < 4; ++nt)
        kf[nt] = *(const half8*)(Ks + min(16 * nt + c, 48) * 40 + 8 * g);

    // ---- QK^T swapped (S^T layout) + exp per mt -> packed b64 Ps writes ----
    const float* cbase = cmb2 + (size_t)(((b & (NWIN - 1)) << 2) | h) * 4096;
#pragma unroll
    for (int mt = 0; mt < 4; ++mt) {
        float cv[4][4];
#pragma unroll
        for (int nt = 0; nt < 4; ++nt)
#pragma unroll
            for (int r = 0; r < 4; ++r)
                cv[nt][r] = cbase[(mt * 16 + nt * 4 + r) * 64 + lane];
        f32x4 smt[4];
#pragma unroll
        for (int nt = 0; nt < 4; ++nt) {
            smt[nt] = (f32x4){0.f, 0.f, 0.f, 0.f};
            smt[nt] = __builtin_amdgcn_mfma_f32_16x16x32_f16(kf[nt], qf[mt], smt[nt], 0, 0, 0);
        }
        const int m = 16 * mt + c;
        if (m < 49) {
#pragma unroll
            for (int nt = 0; nt < 4; ++nt) {
                float p[4];
#pragma unroll
                for (int r = 0; r < 4; ++r) {
                    const int n = 16 * nt + 4 * g + r;
                    p[r] = (n < 49) ? __expf(smt[nt][r] + cv[nt][r]) : 0.f;
                }
                uint2 pk;
                pk.x = packh2(p[0], p[1]);
                pk.y = packh2(p[2], p[3]);
                *(uint2*)(Ps + m * 72 + 16 * nt + 4 * g) = pk;
            }
        }
    }

    // ---- V B-frags hoisted once (vlo/vhi die here) ----
    const _Float16 one16 = (_Float16)1.0f;
    const half8 onesf = {one16, one16, one16, one16, one16, one16, one16, one16};
    const int s0 = c + 32 * gl, s1 = s0 + 16;
    half8 vfk[2][2];
#pragma unroll
    for (int ks = 0; ks < 2; ++ks) {
#pragma unroll
        for (int dt = 0; dt < 2; ++dt) {
            unsigned a0 = __shfl(vlo[2 * ks][dt], s0), a1 = __shfl(vlo[2 * ks + 1][dt], s0);
            unsigned b0 = __shfl(vhi[2 * ks][dt], s0), b1 = __shfl(vhi[2 * ks + 1][dt], s0);
            unsigned c0 = __shfl(vlo[2 * ks][dt], s1), c1 = __shfl(vlo[2 * ks + 1][dt], s1);
            unsigned d0 = __shfl(vhi[2 * ks][dt], s1), d1 = __shfl(vhi[2 * ks + 1][dt], s1);
            uint4 vv;
            vv.x = gh ? a1 : a0; vv.y = gh ? b1 : b0;
            vv.z = gh ? c1 : c0; vv.w = gh ? d1 : d0;
            vfk[ks][dt] = __builtin_bit_cast(half8, vv);
        }
    }

    // ---- PV transposed, two mt-half passes (24 AGPR live): oT = mfma(vf,pf) ----
#pragma unroll
    for (int mhh = 0; mhh < 2; ++mhh) {
        f32x4 oT[2][2], osumT[2];
#pragma unroll
        for (int i = 0; i < 2; ++i) {
            oT[i][0] = (f32x4){0.f, 0.f, 0.f, 0.f};
            oT[i][1] = (f32x4){0.f, 0.f, 0.f, 0.f};
            osumT[i] = (f32x4){0.f, 0.f, 0.f, 0.f};
        }
#pragma unroll
        for (int ks = 0; ks < 2; ++ks) {
#pragma unroll
            for (int i = 0; i < 2; ++i) {
                const int mt = 2 * mhh + i;
                half8 pf = *(const half8*)(Ps + min(16 * mt + c, 48) * 72 + 8 * g + 32 * ks);
                oT[i][0] = __builtin_amdgcn_mfma_f32_16x16x32_f16(vfk[ks][0], pf, oT[i][0], 0, 0, 0);
                oT[i][1] = __builtin_amdgcn_mfma_f32_16x16x32_f16(vfk[ks][1], pf, oT[i][1], 0, 0, 0);
                osumT[i] = __builtin_amdgcn_mfma_f32_16x16x32_f16(onesf, pf, osumT[i], 0, 0, 0);
            }
        }
#pragma unroll
        for (int i = 0; i < 2; ++i) {
            const int m = 16 * (2 * mhh + i) + c;
            if (m < 49) {
                const float iv = 1.0f / osumT[i][0]; // col-sum replicated across rows
#pragma unroll
                for (int dt = 0; dt < 2; ++dt) {
                    uint2 pk;
                    pk.x = packh2(oT[i][dt][0] * iv, oT[i][dt][1] * iv);
                    pk.y = packh2(oT[i][dt][2] * iv, oT[i][dt][3] * iv);
                    *(uint2*)(Os + m * 40 + 16 * dt + 4 * g) = pk;
                }
            }
        }
    }

    __syncthreads(); // all waves' Os slices visible before proj reads

    // ---- in-block proj, two mt-half passes (16 AGPR live) ----
    // A-frag aout[row][32ks+8g+j]: head index = ks -> read wave ks's Os region.
    {
        float* orow = out + (size_t)b * (49 * 128);
#pragma unroll
        for (int mhh = 0; mhh < 2; ++mhh) {
            f32x4 o2[2][2];
#pragma unroll
            for (int i = 0; i < 2; ++i) {
                o2[i][0] = (f32x4){0.f, 0.f, 0.f, 0.f};
                o2[i][1] = (f32x4){0.f, 0.f, 0.f, 0.f};
            }
#pragma unroll
            for (int ks = 0; ks < 4; ++ks) {
                half8 bw[2];
#pragma unroll
                for (int nt = 0; nt < 2; ++nt)
                    bw[nt] = *(const half8*)(pw2 + (((wv * 2 + nt) * 4 + ks) * 64 + lane) * 8);
                const unsigned short* OsK = (const unsigned short*)(smem + ks * PW);
#pragma unroll
                for (int i = 0; i < 2; ++i) {
                    const int row = min(16 * (2 * mhh + i) + c, 48);
                    half8 as = *(const half8*)(OsK + row * 40 + 8 * g);
                    o2[i][0] = __builtin_amdgcn_mfma_f32_16x16x32_f16(as, bw[0], o2[i][0], 0, 0, 0);
                    o2[i][1] = __builtin_amdgcn_mfma_f32_16x16x32_f16(as, bw[1], o2[i][1], 0, 0, 0);
                }
            }
#pragma unroll
            for (int nt = 0; nt < 2; ++nt) {
                const int col = wv * 32 + nt * 16 + c;
                const float bv = proj_b[col];
#pragma unroll
                for (int i = 0; i < 2; ++i) {
#pragma unroll
                    for (int r = 0; r < 4; ++r) {
                        const int m = 16 * (2 * mhh + i) + 4 * g + r;
                        if (m < 49) orow[m * 128 + col] = o2[i][nt][r] + bv;
                    }
                }
            }
        }
    }
}

extern "C" void kernel_launch(void* const* d_in, const int* in_sizes, int n_in,
                              void* d_out, int out_size, void* d_ws, size_t ws_size,
                              hipStream_t stream) {
    const float* x      = (const float*)d_in[0];
    const float* mask   = (const float*)d_in[1];
    const float* qkv_w  = (const float*)d_in[2];
    const float* qkv_b  = (const float*)d_in[3];
    const float* proj_w = (const float*)d_in[4];
    const float* proj_b = (const float*)d_in[5];
    const float* rpb    = (const float*)d_in[6];
    const int*   rpi    = (const int*)d_in[7];
    float* out = (float*)d_out;

    unsigned short* w2  = (unsigned short*)d_ws;   // 49,152 u16 (96 KB)
    unsigned short* pw2 = w2 + 49152;              // 16,384 u16 (32 KB)
    float* cmb2 = (float*)(pw2 + 16384);           // 1,048,576 f32 (4 MB)

    prep_w2<<<dim3(24), 256, 0, stream>>>(qkv_w, w2);
    prep_pw2<<<dim3(8), 256, 0, stream>>>(proj_w, pw2);
    prep_cmb2<<<dim3(4096), 256, 0, stream>>>(rpb, rpi, mask, cmb2);
    attn_fused<<<dim3(B_WIN), 256, 0, stream>>>(x, w2, pw2, qkv_b, cmb2, proj_b, out);
}

// Round 20
// 75.716 us; speedup vs baseline: 2.1701x; 2.1701x over previous
//
#include <hip/hip_runtime.h>

// Window attention, fully fused fp16-MFMA, transposed-output layouts (r14 base).
// r20 = r14 verbatim (best known: 82.0us, no spills) + the three prep kernels
// merged into one dispatch (launch-overhead shave only).
// Plateau note: live state ~130 regs (af[4][4]=64 VGPR) -> 4 waves/SIMD is the
// genuine cap; 102-reg budget spills (r19: WRITE 301MB), extra live state spills
// (r12/r15/r16). Structure is latency-bound at ~19% MfmaUtil / ~20% HBM.
#define B_WIN 4096
#define NTOK 49
#define DIMC 128
#define HEADS 4
#define HD 32
#define NWIN 64
#define MTOT (B_WIN * 49) /* 200704 */
#define SCALE_Q 0.17677669529663687f /* 32^-0.5 */

typedef _Float16 half8 __attribute__((ext_vector_type(8)));
typedef float f32x4 __attribute__((ext_vector_type(4)));
typedef unsigned short ushortv8 __attribute__((ext_vector_type(8)));

__device__ __forceinline__ unsigned short f2h(float f) {
    _Float16 h = (_Float16)f; // RNE
    return __builtin_bit_cast(unsigned short, h);
}
__device__ __forceinline__ unsigned packh2(float a, float b) {
    return (unsigned)f2h(a) | ((unsigned)f2h(b) << 16);
}

struct alignas(8) US4 { unsigned short x, y, z, w; };

#define XSP 136 /* xs / aout_s pitch (u16) */
#define PW 7840 /* per-wave LDS: Qs[49][40] + Ks[49][40]; Ps[49][72] overlays */

// ---------------- merged prep: cmb2 (blocks 0..4095), w2 (4096..4119), pw2 (4120..4127) ----------------
__global__ __launch_bounds__(256) void prep_all(
    const float* __restrict__ rpb, const int* __restrict__ rpi,
    const float* __restrict__ mask, const float* __restrict__ qkv_w,
    const float* __restrict__ proj_w, float* __restrict__ cmb2,
    unsigned short* __restrict__ w2, unsigned short* __restrict__ pw2)
{
    const int blk = blockIdx.x;
    if (blk < 4096) {
        // cmb2[((w*4+h)*64 + mt*16+nt*4+r)*64 + lane] for S^T layout (m=16mt+c, n=16nt+4g+r)
        int id = blk * 256 + threadIdx.x; // < 1048576
        int lane = id & 63, idx = (id >> 6) & 63, wh = id >> 12;
        int h = wh & 3, w = wh >> 2;
        int mt = idx >> 4, nt = (idx >> 2) & 3, r = idx & 3;
        int c = lane & 15, g = lane >> 4;
        int m = 16 * mt + c, n = 16 * nt + 4 * g + r;
        float v = 0.f;
        if (m < 49 && n < 49) {
            int e = m * 49 + n;
            v = rpb[rpi[e] * 4 + h] + mask[w * 2401 + e];
        }
        cmb2[id] = v;
    } else if (blk < 4120) {
        // qkv_w f32 -> fp16, B-frag-ordered
        int id = (blk - 4096) * 256 + threadIdx.x; // < 6144
        if (id < 6144) {
            int lane = id & 63, ks = (id >> 6) & 3, jt = (id >> 8) % 6, h = id / 1536;
            int c = lane & 15, g = lane >> 4;
            int sec = jt >> 1, dhalf = jt & 1;
            int tb = sec * 128 + h * 32 + dhalf * 16;
            const float* src = qkv_w + (size_t)(tb + c) * 128 + 32 * ks + 8 * g;
            ushortv8 p;
#pragma unroll
            for (int j = 0; j < 8; ++j) p[j] = f2h(src[j]);
            *(ushortv8*)(w2 + (size_t)id * 8) = p;
        }
    } else {
        // proj_w f32 -> fp16, B-frag-ordered
        int id = (blk - 4120) * 256 + threadIdx.x; // < 2048
        if (id < 2048) {
            int lane = id & 63, ks = (id >> 6) & 3, j8 = id >> 8;
            int c = lane & 15, g = lane >> 4;
            const float* src = proj_w + (size_t)(j8 * 16 + c) * 128 + 32 * ks + 8 * g;
            ushortv8 p;
#pragma unroll
            for (int j = 0; j < 8; ++j) p[j] = f2h(src[j]);
            *(ushortv8*)(pw2 + (size_t)id * 8) = p;
        }
    }
}

// ---------------- fully fused kernel (r14 verbatim) ----------------
__global__ __launch_bounds__(256, 4) void attn_fused(
    const float* __restrict__ x, const unsigned short* __restrict__ w2,
    const unsigned short* __restrict__ pw2, const float* __restrict__ qkv_b,
    const float* __restrict__ cmb2, const float* __restrict__ proj_b,
    float* __restrict__ out)
{
    __shared__ __align__(16) char smem[4 * PW];
    const int t = threadIdx.x, wv = t >> 6, lane = t & 63;
    const int c = lane & 15, g = lane >> 4;
    const int gl = g & 1, gh = g >> 1;
    const int b = blockIdx.x, h = wv;

    unsigned short* xs = (unsigned short*)smem;               // [49][136] overlay
    unsigned short* aout_s = (unsigned short*)smem;           // [49][136] overlay (later)
    unsigned short* Qs = (unsigned short*)(smem + wv * PW);   // [49][40]
    unsigned short* Ks = Qs + 49 * 40;                        // [49][40]
    unsigned short* Ps = Qs;                                  // [49][72] overlay

    // ---- stage window x: coalesced f32 loads -> fp16 xs ----
    {
        const float* xw = x + (size_t)b * (49 * 128);
#pragma unroll
        for (int it = 0; it < 7; ++it) {
            int idx = it * 256 + t; // 1568 chunks of 4 f32
            if (idx < 1568) {
                int row = idx >> 5, c4 = (idx & 31) * 4;
                float4 v = *(const float4*)(xw + row * 128 + c4);
                US4 p; p.x = f2h(v.x); p.y = f2h(v.y); p.z = f2h(v.z); p.w = f2h(v.w);
                *(US4*)(xs + row * XSP + c4) = p;
            }
        }
    }
    __syncthreads(); // xs staged before frag reads

    // ---- hoist all A-frags from xs (row clamp 48; garbage masked downstream) ----
    half8 af[4][4];
#pragma unroll
    for (int mt = 0; mt < 4; ++mt) {
        const int row = min(16 * mt + c, 48);
#pragma unroll
        for (int ks = 0; ks < 4; ++ks)
            af[mt][ks] = *(const half8*)(xs + row * XSP + 32 * ks + 8 * g);
    }
    __syncthreads(); // all waves done reading xs before Qs/Ks overlay writes

    // ---- qkv gemm: Q/K via swapped mfma (tokens-in-col) -> b64 epi; V -> regs ----
    unsigned vlo[4][2], vhi[4][2]; // V in C-layout packs: [mt][dhalf]
    const unsigned short* wbase = w2 + (size_t)h * 12288;
    half8 bf0[4], bf1[4];
#pragma unroll
    for (int ks = 0; ks < 4; ++ks)
        bf0[ks] = *(const half8*)(wbase + (ks * 64 + lane) * 8);
#pragma unroll
    for (int jt = 0; jt < 6; ++jt) {
        const int sec = jt >> 1, dhalf = jt & 1;
        const int tb = sec * 128 + h * 32 + dhalf * 16;
        if (jt < 5) {
#pragma unroll
            for (int ks = 0; ks < 4; ++ks)
                bf1[ks] = *(const half8*)(wbase + (((jt + 1) * 4 + ks) * 64 + lane) * 8);
        }
        f32x4 acc[4];
#pragma unroll
        for (int mt = 0; mt < 4; ++mt) acc[mt] = (f32x4){0.f, 0.f, 0.f, 0.f};
        if (sec < 2) {
            // swapped: C[i=4g+r -> out-dim][j=c -> token]
#pragma unroll
            for (int ks = 0; ks < 4; ++ks)
#pragma unroll
                for (int mt = 0; mt < 4; ++mt)
                    acc[mt] = __builtin_amdgcn_mfma_f32_16x16x32_f16(bf0[ks], af[mt][ks], acc[mt], 0, 0, 0);
            const float4 bv4 = *(const float4*)(qkv_b + tb + 4 * g);
            const float scl = (sec == 0) ? SCALE_Q : 1.0f;
            unsigned short* dstS = (sec == 0) ? Qs : Ks;
#pragma unroll
            for (int mt = 0; mt < 4; ++mt) {
                const int m = 16 * mt + c;
                if (m < 49) {
                    uint2 pk;
                    pk.x = packh2((acc[mt][0] + bv4.x) * scl, (acc[mt][1] + bv4.y) * scl);
                    pk.y = packh2((acc[mt][2] + bv4.z) * scl, (acc[mt][3] + bv4.w) * scl);
                    *(uint2*)(dstS + m * 40 + dhalf * 16 + 4 * g) = pk;
                }
            }
        } else {
            // original orientation for V (feeds the proven shfl path)
#pragma unroll
            for (int ks = 0; ks < 4; ++ks)
#pragma unroll
                for (int mt = 0; mt < 4; ++mt)
                    acc[mt] = __builtin_amdgcn_mfma_f32_16x16x32_f16(af[mt][ks], bf0[ks], acc[mt], 0, 0, 0);
            const float bv = qkv_b[tb + c];
#pragma unroll
            for (int mt = 0; mt < 4; ++mt) {
                vlo[mt][dhalf] = packh2(acc[mt][0] + bv, acc[mt][1] + bv);
                vhi[mt][dhalf] = packh2(acc[mt][2] + bv, acc[mt][3] + bv);
            }
        }
#pragma unroll
        for (int ks = 0; ks < 4; ++ks) bf0[ks] = bf1[ks];
    }

    // ---- hoist Q/K frags (clamped rows) BEFORE Ps overlay clobbers Qs/Ks ----
    half8 qf[4], kf[4];
#pragma unroll
    for (int mt = 0; mt < 4; ++mt)
        qf[mt] = *(const half8*)(Qs + min(16 * mt + c, 48) * 40 + 8 * g);
#pragma unroll
    for (int nt = 0; nt < 4; ++nt)
        kf[nt] = *(const half8*)(Ks + min(16 * nt + c, 48) * 40 + 8 * g);

    // ---- QK^T swapped (S^T layout) + exp per mt -> packed b64 Ps writes ----
    const float* cbase = cmb2 + (size_t)(((b & (NWIN - 1)) << 2) | h) * 4096;
#pragma unroll
    for (int mt = 0; mt < 4; ++mt) {
        float cv[4][4];
#pragma unroll
        for (int nt = 0; nt < 4; ++nt)
#pragma unroll
            for (int r = 0; r < 4; ++r)
                cv[nt][r] = cbase[(mt * 16 + nt * 4 + r) * 64 + lane];
        f32x4 smt[4];
#pragma unroll
        for (int nt = 0; nt < 4; ++nt) {
            smt[nt] = (f32x4){0.f, 0.f, 0.f, 0.f};
            smt[nt] = __builtin_amdgcn_mfma_f32_16x16x32_f16(kf[nt], qf[mt], smt[nt], 0, 0, 0);
        }
        const int m = 16 * mt + c;
        if (m < 49) {
#pragma unroll
            for (int nt = 0; nt < 4; ++nt) {
                float p[4];
#pragma unroll
                for (int r = 0; r < 4; ++r) {
                    const int n = 16 * nt + 4 * g + r;
                    p[r] = (n < 49) ? __expf(smt[nt][r] + cv[nt][r]) : 0.f;
                }
                uint2 pk;
                pk.x = packh2(p[0], p[1]);
                pk.y = packh2(p[2], p[3]);
                *(uint2*)(Ps + m * 72 + 16 * nt + 4 * g) = pk;
            }
        }
    }

    // ---- PV transposed: oT = mfma(vf, pf), osumT = mfma(ones, pf) ----
    f32x4 oT[4][2], osumT[4];
#pragma unroll
    for (int mt = 0; mt < 4; ++mt) {
        oT[mt][0] = (f32x4){0.f, 0.f, 0.f, 0.f};
        oT[mt][1] = (f32x4){0.f, 0.f, 0.f, 0.f};
        osumT[mt] = (f32x4){0.f, 0.f, 0.f, 0.f};
    }
    const _Float16 one16 = (_Float16)1.0f;
    const half8 onesf = {one16, one16, one16, one16, one16, one16, one16, one16};

    const int s0 = c + 32 * gl, s1 = s0 + 16;
#pragma unroll
    for (int ks = 0; ks < 2; ++ks) {
        half8 vf[2];
#pragma unroll
        for (int dt = 0; dt < 2; ++dt) {
            unsigned a0 = __shfl(vlo[2 * ks][dt], s0), a1 = __shfl(vlo[2 * ks + 1][dt], s0);
            unsigned b0 = __shfl(vhi[2 * ks][dt], s0), b1 = __shfl(vhi[2 * ks + 1][dt], s0);
            unsigned c0 = __shfl(vlo[2 * ks][dt], s1), c1 = __shfl(vlo[2 * ks + 1][dt], s1);
            unsigned d0 = __shfl(vhi[2 * ks][dt], s1), d1 = __shfl(vhi[2 * ks + 1][dt], s1);
            uint4 vv;
            vv.x = gh ? a1 : a0; vv.y = gh ? b1 : b0;
            vv.z = gh ? c1 : c0; vv.w = gh ? d1 : d0;
            vf[dt] = __builtin_bit_cast(half8, vv);
        }
#pragma unroll
        for (int mt = 0; mt < 4; ++mt) {
            half8 pf = *(const half8*)(Ps + min(16 * mt + c, 48) * 72 + 8 * g + 32 * ks);
            oT[mt][0] = __builtin_amdgcn_mfma_f32_16x16x32_f16(vf[0], pf, oT[mt][0], 0, 0, 0);
            oT[mt][1] = __builtin_amdgcn_mfma_f32_16x16x32_f16(vf[1], pf, oT[mt][1], 0, 0, 0);
            osumT[mt] = __builtin_amdgcn_mfma_f32_16x16x32_f16(onesf, pf, osumT[mt], 0, 0, 0);
        }
    }

    __syncthreads(); // all waves done with Ps/Qs/Ks before aout_s overlays the front

    // ---- normalized O^T -> aout_s, packed b64 (lane holds 4 consecutive d) ----
#pragma unroll
    for (int mt = 0; mt < 4; ++mt) {
        const int m = 16 * mt + c;
        if (m < 49) {
            const float iv = 1.0f / osumT[mt][0]; // col-sum replicated across rows
#pragma unroll
            for (int dt = 0; dt < 2; ++dt) {
                uint2 pk;
                pk.x = packh2(oT[mt][dt][0] * iv, oT[mt][dt][1] * iv);
                pk.y = packh2(oT[mt][dt][2] * iv, oT[mt][dt][3] * iv);
                *(uint2*)(aout_s + m * XSP + h * HD + 16 * dt + 4 * g) = pk;
            }
        }
    }
    __syncthreads(); // aout_s complete before proj reads

    // ---- in-block proj: this wave computes out cols [wv*32, wv*32+32) ----
    {
        f32x4 o2[4][2];
#pragma unroll
        for (int mt = 0; mt < 4; ++mt) {
            o2[mt][0] = (f32x4){0.f, 0.f, 0.f, 0.f};
            o2[mt][1] = (f32x4){0.f, 0.f, 0.f, 0.f};
        }
#pragma unroll
        for (int ks = 0; ks < 4; ++ks) {
            half8 bw[2];
#pragma unroll
            for (int nt = 0; nt < 2; ++nt)
                bw[nt] = *(const half8*)(pw2 + (((wv * 2 + nt) * 4 + ks) * 64 + lane) * 8);
#pragma unroll
            for (int mt = 0; mt < 4; ++mt) {
                half8 as = *(const half8*)(aout_s + min(16 * mt + c, 48) * XSP + 32 * ks + 8 * g);
                o2[mt][0] = __builtin_amdgcn_mfma_f32_16x16x32_f16(as, bw[0], o2[mt][0], 0, 0, 0);
                o2[mt][1] = __builtin_amdgcn_mfma_f32_16x16x32_f16(as, bw[1], o2[mt][1], 0, 0, 0);
            }
        }
        float* orow = out + (size_t)b * (49 * 128);
#pragma unroll
        for (int nt = 0; nt < 2; ++nt) {
            const int col = wv * 32 + nt * 16 + c;
            const float bv = proj_b[col];
#pragma unroll
            for (int mt = 0; mt < 4; ++mt) {
#pragma unroll
                for (int r = 0; r < 4; ++r) {
                    const int m = 16 * mt + 4 * g + r;
                    if (m < 49) orow[m * 128 + col] = o2[mt][nt][r] + bv;
                }
            }
        }
    }
}

extern "C" void kernel_launch(void* const* d_in, const int* in_sizes, int n_in,
                              void* d_out, int out_size, void* d_ws, size_t ws_size,
                              hipStream_t stream) {
    const float* x      = (const float*)d_in[0];
    const float* mask   = (const float*)d_in[1];
    const float* qkv_w  = (const float*)d_in[2];
    const float* qkv_b  = (const float*)d_in[3];
    const float* proj_w = (const float*)d_in[4];
    const float* proj_b = (const float*)d_in[5];
    const float* rpb    = (const float*)d_in[6];
    const int*   rpi    = (const int*)d_in[7];
    float* out = (float*)d_out;

    unsigned short* w2  = (unsigned short*)d_ws;   // 49,152 u16 (96 KB)
    unsigned short* pw2 = w2 + 49152;              // 16,384 u16 (32 KB)
    float* cmb2 = (float*)(pw2 + 16384);           // 1,048,576 f32 (4 MB)

    prep_all<<<dim3(4128), 256, 0, stream>>>(rpb, rpi, mask, qkv_w, proj_w, cmb2, w2, pw2);
    attn_fused<<<dim3(B_WIN), 256, 0, stream>>>(x, w2, pw2, qkv_b, cmb2, proj_b, out);
}